// Round 5
// baseline (422.338 us; speedup 1.0000x reference)
//
#include <hip/hip_runtime.h>
#include <hip/hip_bf16.h>

#define NNODES 100000
#define NEDGES 1600000
#define KDIM 256
#define ODIM 128
#define NXCD 8            // counts replicated per-XCD; selected by HW_REG_XCC_ID
#define NB_SCAN 391       // ceil(100000 / 256)
#define EDGE_CAP 1900032  // 1.6M + 3*100000, rounded up a bit
#define ESTRIDE 400000    // NEDGES / 4
#define GEMM_BLOCKS 1563  // ceil(100000 / 64)
#define RANK_BLOCKS 1563  // ceil(400000 / 256)

typedef __attribute__((ext_vector_type(8))) short short8;
typedef __attribute__((ext_vector_type(4))) float floatx4;

// round-to-nearest-even f32 -> bf16 (inputs are finite Gaussians; no NaN handling needed)
static __device__ __forceinline__ short f2bf(float f) {
  union { float f; unsigned u; } x; x.f = f;
  unsigned r = (x.u + 0x7fffu + ((x.u >> 16) & 1u)) >> 16;
  return (short)r;
}

__global__ void conv_w_kernel(const float* __restrict__ W, short* __restrict__ Wb) {
  int i = blockIdx.x * 256 + threadIdx.x;
  if (i < ODIM * KDIM) Wb[i] = f2bf(W[i]);
}

// STANDALONE rank kernel: runs with an otherwise-idle L2, so each XCD's 400 KB
// counts copy stays L2-resident and the atomics are L2-hit RMWs. XCD-local
// workgroup-scope relaxed atomics; rank stores (xcc<<8)|local_rank.
__global__ __launch_bounds__(256) void rank_kernel(const int* __restrict__ rows,
                                                   unsigned* __restrict__ counts,
                                                   unsigned short* __restrict__ rank) {
  unsigned xcc;
  asm("s_getreg_b32 %0, hwreg(HW_REG_XCC_ID)" : "=s"(xcc));
  xcc &= 7u;
  unsigned* cbase = counts + (size_t)xcc * NNODES;
  int i = blockIdx.x * 256 + threadIdx.x;
#pragma unroll
  for (int j = 0; j < 4; j++) {
    int e = i + j * ESTRIDE;
    if (e < NEDGES) {
      int r = rows[e];
      unsigned old = __hip_atomic_fetch_add(&cbase[r], 1u, __ATOMIC_RELAXED,
                                            __HIP_MEMORY_SCOPE_WORKGROUP);
      rank[e] = (unsigned short)((xcc << 8) | old);
    }
  }
}

// LDS-staged gemm: 64 rows/block, 256 threads. The X tile is read fully
// COALESCED (wave instruction j: lanes 0..63 read consecutive float4s = one
// whole 1 KB row), converted to bf16 in registers, ds_write_b64 into a
// XOR-swizzled [64][256] bf16 tile (byte ^= (row&7)<<4; same swizzle on read
// -> <=2-way bank aliasing, free). This replaces the old 1024B-strided
// 16-rows-per-instruction X pattern that capped at ~850 GB/s.
// Compute: wave w owns rows [w*16, w*16+16); 8 k-steps; A-frag from LDS
// (ds_read_b128), B-frag from global Wb (64 KB, L1/L2-hot).
// D layout: col = t*16 + (lane&15), row = quad*4 + reg  [m89 layout]
// H stored PACKED: u32 word j = (bf16 col j) | (bf16 col j+64)<<16.
__global__ __launch_bounds__(256) void gemm_kernel(
    const float* __restrict__ X, const short* __restrict__ Wb,
    const float* __restrict__ bias, unsigned* __restrict__ H2) {
  __shared__ short As[64 * 256];  // 32 KB bf16 tile, row stride 512 B, swizzled
  const int tid = threadIdx.x;
  const int wave = tid >> 6;
  const int lane = tid & 63;
  const int bRow0 = blockIdx.x * 64;
  const float4 zf4 = {0.f, 0.f, 0.f, 0.f};

  // ---- stage: 16 coalesced 1KB wave-loads, 2 batches of 8 in flight ----
#pragma unroll
  for (int b = 0; b < 2; b++) {
    float4 v[8];
#pragma unroll
    for (int j2 = 0; j2 < 8; j2++) {
      const int rl = (b * 8 + j2) * 4 + wave;          // local row 0..63
      const int gr = bRow0 + rl;
      v[j2] = (gr < NNODES) ? *(const float4*)(X + (size_t)gr * KDIM + lane * 4) : zf4;
    }
#pragma unroll
    for (int j2 = 0; j2 < 8; j2++) {
      const int rl = (b * 8 + j2) * 4 + wave;
      union { short s[4]; int2 i2; } u;
      u.s[0] = f2bf(v[j2].x); u.s[1] = f2bf(v[j2].y);
      u.s[2] = f2bf(v[j2].z); u.s[3] = f2bf(v[j2].w);
      const int off = rl * 512 + ((lane * 8) ^ ((rl & 7) << 4));
      *(int2*)((char*)As + off) = u.i2;
    }
  }
  __syncthreads();

  // ---- compute ----
  const int l16 = lane & 15;
  const int quad = lane >> 4;
  const int rl = wave * 16 + l16;                      // local A row
  const unsigned sw = (unsigned)((rl & 7) << 4);
  const char* abase = (const char*)As + rl * 512;

  floatx4 acc[8];
#pragma unroll
  for (int t = 0; t < 8; t++) acc[t] = (floatx4){0.f, 0.f, 0.f, 0.f};

#pragma unroll
  for (int k0 = 0; k0 < 8; k0++) {
    const short8 a = *(const short8*)(abase + (((unsigned)(k0 * 64 + quad * 16)) ^ sw));
    const short* bp = Wb + k0 * 32 + quad * 8;
#pragma unroll
    for (int t = 0; t < 8; t++) {
      short8 bfrag = *(const short8*)(bp + (size_t)(t * 16 + l16) * KDIM);
      acc[t] = __builtin_amdgcn_mfma_f32_16x16x32_bf16(a, bfrag, acc[t], 0, 0, 0);
    }
  }

  const int rowBase = bRow0 + wave * 16;
#pragma unroll
  for (int t = 0; t < 4; t++) {
    const int cl = t * 16 + l16;
    const float blo = bias[cl];
    const float bhi = bias[cl + 64];
#pragma unroll
    for (int r = 0; r < 4; r++) {
      const int row = rowBase + quad * 4 + r;
      if (row < NNODES) {
        unsigned lo = (unsigned short)f2bf(acc[t][r] + blo);
        unsigned hi = (unsigned short)f2bf(acc[t + 4][r] + bhi);
        H2[(size_t)row * 64 + cl] = lo | (hi << 16);
      }
    }
  }
}

// scan1: one node per thread. Sum the node's 8 per-XCD counts, pad total to
// multiple of 4 (spmm reads int4 pairs), block-level exclusive scan.
__global__ void scan1_kernel(const unsigned* __restrict__ counts, int* __restrict__ chunkExcl,
                             int* __restrict__ blockSums) {
  __shared__ int s[256];
  int t = threadIdx.x;
  int n = blockIdx.x * 256 + t;
  int sum = 0;
  if (n < NNODES) {
    int s0 = 0;
#pragma unroll
    for (int x = 0; x < NXCD; x++) s0 += (int)counts[(size_t)x * NNODES + n];
    sum = (s0 + 3) & ~3;  // pad segment to multiple of 4 records
  }
  s[t] = sum;
  __syncthreads();
  for (int o = 1; o < 256; o <<= 1) {
    int add = (t >= o) ? s[t - o] : 0;
    __syncthreads();
    s[t] += add;
    __syncthreads();
  }
  if (n < NNODES) chunkExcl[n] = s[t] - sum;
  if (t == 255) blockSums[blockIdx.x] = s[255];
}

// single-block exclusive scan of the 391 chunk totals; writes offsets[NNODES] = total
__global__ void scan2_kernel(const int* __restrict__ blockSums, int* __restrict__ blockBase,
                             int* __restrict__ offsets) {
  __shared__ int s[512];
  int t = threadIdx.x;
  int v = (t < NB_SCAN) ? blockSums[t] : 0;
  s[t] = v;
  __syncthreads();
  for (int o = 1; o < 512; o <<= 1) {
    int add = (t >= o) ? s[t - o] : 0;
    __syncthreads();
    s[t] += add;
    __syncthreads();
  }
  if (t < NB_SCAN) blockBase[t] = s[t] - v;
  if (t == 511) offsets[NNODES] = s[511];
}

// scan3: per node, write offsets[n] (segment start, multiple of 4) and convert the
// node's 8 per-XCD COUNTS in place into ABSOLUTE per-XCD base positions.
__global__ void scan3_kernel(const int* __restrict__ chunkExcl, const int* __restrict__ blockBase,
                             unsigned* __restrict__ counts, int* __restrict__ offsets) {
  int n = blockIdx.x * 256 + threadIdx.x;
  if (n >= NNODES) return;
  int run = chunkExcl[n] + blockBase[n >> 8];
  offsets[n] = run;
#pragma unroll
  for (int x = 0; x < NXCD; x++) {
    int c = (int)counts[(size_t)x * NNODES + n];
    counts[(size_t)x * NNODES + n] = (unsigned)run;
    run += c;
  }
}

// Atomic-free placement: pos = xcdBase[xcc][row] + local_rank.
__global__ void place_kernel(const int* __restrict__ rows, const int* __restrict__ cols,
                             const float* __restrict__ vals,
                             const unsigned short* __restrict__ rank,
                             const unsigned* __restrict__ sbase, int2* __restrict__ edges) {
  int i = blockIdx.x * 256 + threadIdx.x;
#pragma unroll
  for (int j = 0; j < 4; j++) {
    int e = i + j * ESTRIDE;
    if (e < NEDGES) {
      int r = rows[e];
      unsigned rk = rank[e];
      int p = (int)sbase[(size_t)(rk >> 8) * NNODES + r] + (int)(rk & 255u);
      int2 rec;
      rec.x = cols[e];
      rec.y = __float_as_int(vals[e]);
      edges[p] = rec;
    }
  }
}

// One wave per output row. Lane owns channels {lane, lane+64} (one uint = packed
// bf16 pair per gathered H row -> 256 B coalesced per edge). Segments are padded
// to a multiple of 4 records (pad = {col 0, val 0}) -> no tail loop.
__global__ __launch_bounds__(256) void spmm_kernel(const int* __restrict__ offsets,
                                                   const int2* __restrict__ edges,
                                                   const unsigned* __restrict__ H2,
                                                   float* __restrict__ out) {
  const int lane = threadIdx.x & 63;
  const int row = blockIdx.x * 4 + (threadIdx.x >> 6);
  if (row >= NNODES) return;
  const int s = offsets[row];      // multiple of 4
  const int e = offsets[row + 1];
  float ax = 0.f, ay = 0.f;
  for (int i = s; i < e; i += 4) {
    const int4 p01 = *(const int4*)(edges + i);      // 16 B aligned (s % 4 == 0)
    const int4 p23 = *(const int4*)(edges + i + 2);
    const unsigned h0 = H2[(size_t)p01.x * 64 + lane];
    const unsigned h1 = H2[(size_t)p01.z * 64 + lane];
    const unsigned h2 = H2[(size_t)p23.x * 64 + lane];
    const unsigned h3 = H2[(size_t)p23.z * 64 + lane];
    const float v0 = __int_as_float(p01.y);
    const float v1 = __int_as_float(p01.w);
    const float v2 = __int_as_float(p23.y);
    const float v3 = __int_as_float(p23.w);
    ax += v0 * __uint_as_float(h0 << 16);            // col = lane
    ay += v0 * __uint_as_float(h0 & 0xffff0000u);    // col = lane + 64
    ax += v1 * __uint_as_float(h1 << 16);
    ay += v1 * __uint_as_float(h1 & 0xffff0000u);
    ax += v2 * __uint_as_float(h2 << 16);
    ay += v2 * __uint_as_float(h2 & 0xffff0000u);
    ax += v3 * __uint_as_float(h3 << 16);
    ay += v3 * __uint_as_float(h3 & 0xffff0000u);
  }
  out[(size_t)row * 128 + lane] = ax;
  out[(size_t)row * 128 + 64 + lane] = ay;
}

extern "C" void kernel_launch(void* const* d_in, const int* in_sizes, int n_in,
                              void* d_out, int out_size, void* d_ws, size_t ws_size,
                              hipStream_t stream) {
  const float* X = (const float*)d_in[0];
  const int* erow = (const int*)d_in[1];
  const int* ecol = (const int*)d_in[2];
  const float* eval = (const float*)d_in[3];
  const float* W = (const float*)d_in[4];
  const float* bias = (const float*)d_in[5];
  float* out = (float*)d_out;

  char* ws = (char*)d_ws;
  size_t off = 0;
  auto alloc = [&](size_t bytes) -> char* {
    char* p = ws + off;
    off += (bytes + 255) & ~(size_t)255;
    return p;
  };
  unsigned* Hb = (unsigned*)alloc((size_t)NNODES * 64 * 4);                // 25.6 MB packed
  short* Wb = (short*)alloc((size_t)ODIM * KDIM * 2);                      // 64 KB
  unsigned* counts = (unsigned*)alloc((size_t)NXCD * NNODES * 4);          // 3.2 MB (-> bases)
  int* chunkExcl = (int*)alloc((size_t)NNODES * 4);
  int* offsets = (int*)alloc((size_t)(NNODES + 1) * 4);
  int* blockSums = (int*)alloc((size_t)NB_SCAN * 4);
  int* blockBase = (int*)alloc((size_t)NB_SCAN * 4);
  unsigned short* rank = (unsigned short*)alloc((size_t)NEDGES * 2);  // 3.2 MB
  int2* edges = (int2*)alloc((size_t)EDGE_CAP * 8);  // 15.2 MB, padded CSR records

  hipMemsetAsync(counts, 0, (size_t)NXCD * NNODES * 4, stream);
  hipMemsetAsync(edges, 0, (size_t)EDGE_CAP * 8, stream);  // pad records = {col 0, val 0}
  conv_w_kernel<<<(ODIM * KDIM + 255) / 256, 256, 0, stream>>>(W, Wb);
  rank_kernel<<<RANK_BLOCKS, 256, 0, stream>>>(erow, counts, rank);
  gemm_kernel<<<GEMM_BLOCKS, 256, 0, stream>>>(X, Wb, bias, Hb);
  scan1_kernel<<<NB_SCAN, 256, 0, stream>>>(counts, chunkExcl, blockSums);
  scan2_kernel<<<1, 512, 0, stream>>>(blockSums, blockBase, offsets);
  scan3_kernel<<<NB_SCAN, 256, 0, stream>>>(chunkExcl, blockBase, counts, offsets);
  place_kernel<<<(ESTRIDE + 255) / 256, 256, 0, stream>>>(erow, ecol, eval, rank, counts, edges);
  spmm_kernel<<<(NNODES + 3) / 4, 256, 0, stream>>>(offsets, edges, (const unsigned*)Hb, out);
}

// Round 8
// 398.722 us; speedup vs baseline: 1.0592x; 1.0592x over previous
//
#include <hip/hip_runtime.h>
#include <hip/hip_bf16.h>

#define NNODES 100000
#define NEDGES 1600000
#define KDIM 256
#define ODIM 128
#define NXCD 8            // counts replicated per-XCD; selected by HW_REG_XCC_ID
#define NB_SCAN 391       // ceil(100000 / 256)
#define EDGE_CAP 1900032  // 1.6M + 3*100000, rounded up a bit
#define GEMM_BLOCKS 1563  // ceil(100000 / 64)
#define RANK_BLOCKS 1563  // ceil(400000 / 256); thread i owns edges [4i, 4i+4)
#define CONV_BLOCKS 128   // ceil(32768 / 256)

typedef __attribute__((ext_vector_type(8))) short short8;
typedef __attribute__((ext_vector_type(4))) float floatx4;

// round-to-nearest-even f32 -> bf16 (inputs are finite Gaussians; no NaN handling needed)
static __device__ __forceinline__ short f2bf(float f) {
  union { float f; unsigned u; } x; x.f = f;
  unsigned r = (x.u + 0x7fffu + ((x.u >> 16) & 1u)) >> 16;
  return (short)r;
}

// K1: conv_w (128 blocks) || rank (1563 blocks) — independent, fused to overlap.
// rank: XCD-local workgroup-scope relaxed atomics on the per-XCD counts copy
// (8 x 400 KB, L2-resident); rank stores (xcc<<8)|local_rank.
// EXACT partition: thread i owns edges [4i, 4i+4) (NEDGES % 4 == 0 -> no tail,
// no double-processing).
__global__ __launch_bounds__(256) void conv_rank_kernel(
    const float* __restrict__ W, short* __restrict__ Wb,
    const int* __restrict__ rows, unsigned* __restrict__ counts,
    unsigned short* __restrict__ rank) {
  if (blockIdx.x < CONV_BLOCKS) {
    int i = blockIdx.x * 256 + threadIdx.x;
    if (i < ODIM * KDIM) Wb[i] = f2bf(W[i]);
    return;
  }
  unsigned xcc;
  asm("s_getreg_b32 %0, hwreg(HW_REG_XCC_ID)" : "=s"(xcc));
  xcc &= 7u;
  unsigned* cbase = counts + (size_t)xcc * NNODES;
  const int e0 = ((blockIdx.x - CONV_BLOCKS) * 256 + threadIdx.x) * 4;
  if (e0 < NEDGES) {
    const int4 r4 = *(const int4*)(rows + e0);
    const unsigned o0 = __hip_atomic_fetch_add(&cbase[r4.x], 1u, __ATOMIC_RELAXED,
                                               __HIP_MEMORY_SCOPE_WORKGROUP);
    const unsigned o1 = __hip_atomic_fetch_add(&cbase[r4.y], 1u, __ATOMIC_RELAXED,
                                               __HIP_MEMORY_SCOPE_WORKGROUP);
    const unsigned o2 = __hip_atomic_fetch_add(&cbase[r4.z], 1u, __ATOMIC_RELAXED,
                                               __HIP_MEMORY_SCOPE_WORKGROUP);
    const unsigned o3 = __hip_atomic_fetch_add(&cbase[r4.w], 1u, __ATOMIC_RELAXED,
                                               __HIP_MEMORY_SCOPE_WORKGROUP);
    ushort4 rk;
    rk.x = (unsigned short)((xcc << 8) | o0);
    rk.y = (unsigned short)((xcc << 8) | o1);
    rk.z = (unsigned short)((xcc << 8) | o2);
    rk.w = (unsigned short)((xcc << 8) | o3);
    *(ushort4*)(rank + e0) = rk;   // 8 B aligned (e0 % 4 == 0)
  }
}

// K2: scan1 (first 391 blocks — depends only on rank, runs concurrently with
// gemm) || gemm (1563 blocks — round-3 structure, measured 90 us, no LDS so
// the scan blocks cost nothing in residency).
__global__ __launch_bounds__(256) void gemm_scan1_kernel(
    const float* __restrict__ X, const short* __restrict__ Wb,
    const float* __restrict__ bias, unsigned* __restrict__ H2,
    const unsigned* __restrict__ counts, int* __restrict__ chunkExcl,
    int* __restrict__ blockSums) {
  __shared__ int s[256];
  if (blockIdx.x < NB_SCAN) {
    int t = threadIdx.x;
    int n = blockIdx.x * 256 + t;
    int sum = 0;
    if (n < NNODES) {
      int s0 = 0;
#pragma unroll
      for (int x = 0; x < NXCD; x++) s0 += (int)counts[(size_t)x * NNODES + n];
      sum = (s0 + 3) & ~3;  // pad segment to multiple of 4 records
    }
    s[t] = sum;
    __syncthreads();
    for (int o = 1; o < 256; o <<= 1) {
      int add = (t >= o) ? s[t - o] : 0;
      __syncthreads();
      s[t] += add;
      __syncthreads();
    }
    if (n < NNODES) chunkExcl[n] = s[t] - sum;
    if (t == 255) blockSums[blockIdx.x] = s[255];
    return;
  }
  // ---- gemm path ----
  const int gb = blockIdx.x - NB_SCAN;
  const int lane = threadIdx.x & 63;
  const int wave = threadIdx.x >> 6;
  const int l16 = lane & 15;
  const int quad = lane >> 4;
  const int rowBase = gb * 64 + wave * 16;
  const int arow = rowBase + l16;
  const bool inb = arow < NNODES;
  const float4 zf4 = {0.f, 0.f, 0.f, 0.f};
  const float4* xp = (const float4*)(X + (size_t)(inb ? arow : 0) * KDIM + quad * 8);

  floatx4 acc[8];
#pragma unroll
  for (int t = 0; t < 8; t++) acc[t] = (floatx4){0.f, 0.f, 0.f, 0.f};

  float4 c0 = inb ? xp[0] : zf4;
  float4 c1 = inb ? xp[1] : zf4;
#pragma unroll
  for (int k0 = 0; k0 < 8; k0++) {
    float4 n0, n1;
    if (k0 < 7) {
      n0 = inb ? xp[(k0 + 1) * 8] : zf4;
      n1 = inb ? xp[(k0 + 1) * 8 + 1] : zf4;
    }
    short8 a;
    a[0] = f2bf(c0.x); a[1] = f2bf(c0.y); a[2] = f2bf(c0.z); a[3] = f2bf(c0.w);
    a[4] = f2bf(c1.x); a[5] = f2bf(c1.y); a[6] = f2bf(c1.z); a[7] = f2bf(c1.w);
    const short* bp = Wb + k0 * 32 + quad * 8;
#pragma unroll
    for (int t = 0; t < 8; t++) {
      short8 b = *(const short8*)(bp + (size_t)(t * 16 + l16) * KDIM);
      acc[t] = __builtin_amdgcn_mfma_f32_16x16x32_bf16(a, b, acc[t], 0, 0, 0);
    }
    if (k0 < 7) { c0 = n0; c1 = n1; }
  }

#pragma unroll
  for (int t = 0; t < 4; t++) {
    const int cl = t * 16 + l16;
    const float blo = bias[cl];
    const float bhi = bias[cl + 64];
#pragma unroll
    for (int r = 0; r < 4; r++) {
      const int row = rowBase + quad * 4 + r;
      if (row < NNODES) {
        unsigned lo = (unsigned short)f2bf(acc[t][r] + blo);
        unsigned hi = (unsigned short)f2bf(acc[t + 4][r] + bhi);
        H2[(size_t)row * 64 + cl] = lo | (hi << 16);
      }
    }
  }
}

// K3: merged scan2+scan3+pad-write. 391 blocks x 512 threads. Each block
// REDUNDANTLY scans the 391 blockSums in LDS to get its base — eliminates the
// serial single-block scan2 dispatch. Then per node: write offsets[n], convert
// the 8 per-XCD counts in place into absolute base positions, and zero the
// <=3 pad records directly (replaces the 15.2 MB edges memset; with exact edge
// partitioning, place covers [run, run+deg) and pads cover the rest, so every
// slot spmm reads is written every iteration).
__global__ __launch_bounds__(512) void scan23_kernel(
    const int* __restrict__ blockSums, const int* __restrict__ chunkExcl,
    unsigned* __restrict__ counts, int* __restrict__ offsets,
    int2* __restrict__ edges) {
  __shared__ int s[512];
  const int t = threadIdx.x;
  s[t] = (t < NB_SCAN) ? blockSums[t] : 0;
  __syncthreads();
  for (int o = 1; o < 512; o <<= 1) {
    int add = (t >= o) ? s[t - o] : 0;
    __syncthreads();
    s[t] += add;
    __syncthreads();
  }
  // s[] now holds the inclusive scan of blockSums
  const int myBase = (blockIdx.x == 0) ? 0 : s[blockIdx.x - 1];
  if (blockIdx.x == 0 && t == 0) offsets[NNODES] = s[NB_SCAN - 1];
  if (t < 256) {
    const int n = blockIdx.x * 256 + t;
    if (n < NNODES) {
      const int run = chunkExcl[n] + myBase;   // multiple of 4
      offsets[n] = run;
      int c[NXCD];
      int deg = 0;
#pragma unroll
      for (int x = 0; x < NXCD; x++) {
        c[x] = (int)counts[(size_t)x * NNODES + n];
        deg += c[x];
      }
      int acc2 = run;
#pragma unroll
      for (int x = 0; x < NXCD; x++) {
        counts[(size_t)x * NNODES + n] = (unsigned)acc2;
        acc2 += c[x];
      }
      const int padded = (deg + 3) & ~3;
      const int2 zrec = {0, 0};
      for (int p = run + deg; p < run + padded; p++) edges[p] = zrec;  // pad = {col 0, val 0}
    }
  }
}

// K4: atomic-free placement: pos = xcdBase[xcc][row] + local_rank. Exact
// 4-contiguous partition, vectorized int4/float4/ushort4 loads.
__global__ __launch_bounds__(256) void place_kernel(
    const int* __restrict__ rows, const int* __restrict__ cols,
    const float* __restrict__ vals, const unsigned short* __restrict__ rank,
    const unsigned* __restrict__ sbase, int2* __restrict__ edges) {
  const int e0 = (blockIdx.x * 256 + threadIdx.x) * 4;
  if (e0 < NEDGES) {
    const int4 r4 = *(const int4*)(rows + e0);
    const int4 c4 = *(const int4*)(cols + e0);
    const float4 v4 = *(const float4*)(vals + e0);
    const ushort4 k4 = *(const ushort4*)(rank + e0);
    int2 rec;
    rec.x = c4.x; rec.y = __float_as_int(v4.x);
    edges[(int)sbase[(size_t)(k4.x >> 8) * NNODES + r4.x] + (int)(k4.x & 255u)] = rec;
    rec.x = c4.y; rec.y = __float_as_int(v4.y);
    edges[(int)sbase[(size_t)(k4.y >> 8) * NNODES + r4.y] + (int)(k4.y & 255u)] = rec;
    rec.x = c4.z; rec.y = __float_as_int(v4.z);
    edges[(int)sbase[(size_t)(k4.z >> 8) * NNODES + r4.z] + (int)(k4.z & 255u)] = rec;
    rec.x = c4.w; rec.y = __float_as_int(v4.w);
    edges[(int)sbase[(size_t)(k4.w >> 8) * NNODES + r4.w] + (int)(k4.w & 255u)] = rec;
  }
}

// K5: one wave per output row. Lane owns channels {lane, lane+64} (one uint =
// packed bf16 pair per gathered H row -> 256 B coalesced per edge). Segments
// padded to multiple of 4 records (pads are {col 0, val 0}) -> no tail loop.
__global__ __launch_bounds__(256) void spmm_kernel(const int* __restrict__ offsets,
                                                   const int2* __restrict__ edges,
                                                   const unsigned* __restrict__ H2,
                                                   float* __restrict__ out) {
  const int lane = threadIdx.x & 63;
  const int row = blockIdx.x * 4 + (threadIdx.x >> 6);
  if (row >= NNODES) return;
  const int s = offsets[row];      // multiple of 4
  const int e = offsets[row + 1];
  float ax = 0.f, ay = 0.f;
  for (int i = s; i < e; i += 4) {
    const int4 p01 = *(const int4*)(edges + i);      // 16 B aligned (s % 4 == 0)
    const int4 p23 = *(const int4*)(edges + i + 2);
    const unsigned h0 = H2[(size_t)p01.x * 64 + lane];
    const unsigned h1 = H2[(size_t)p01.z * 64 + lane];
    const unsigned h2 = H2[(size_t)p23.x * 64 + lane];
    const unsigned h3 = H2[(size_t)p23.z * 64 + lane];
    const float v0 = __int_as_float(p01.y);
    const float v1 = __int_as_float(p01.w);
    const float v2 = __int_as_float(p23.y);
    const float v3 = __int_as_float(p23.w);
    ax += v0 * __uint_as_float(h0 << 16);            // col = lane
    ay += v0 * __uint_as_float(h0 & 0xffff0000u);    // col = lane + 64
    ax += v1 * __uint_as_float(h1 << 16);
    ay += v1 * __uint_as_float(h1 & 0xffff0000u);
    ax += v2 * __uint_as_float(h2 << 16);
    ay += v2 * __uint_as_float(h2 & 0xffff0000u);
    ax += v3 * __uint_as_float(h3 << 16);
    ay += v3 * __uint_as_float(h3 & 0xffff0000u);
  }
  out[(size_t)row * 128 + lane] = ax;
  out[(size_t)row * 128 + 64 + lane] = ay;
}

extern "C" void kernel_launch(void* const* d_in, const int* in_sizes, int n_in,
                              void* d_out, int out_size, void* d_ws, size_t ws_size,
                              hipStream_t stream) {
  const float* X = (const float*)d_in[0];
  const int* erow = (const int*)d_in[1];
  const int* ecol = (const int*)d_in[2];
  const float* eval = (const float*)d_in[3];
  const float* W = (const float*)d_in[4];
  const float* bias = (const float*)d_in[5];
  float* out = (float*)d_out;

  char* ws = (char*)d_ws;
  size_t off = 0;
  auto alloc = [&](size_t bytes) -> char* {
    char* p = ws + off;
    off += (bytes + 255) & ~(size_t)255;
    return p;
  };
  unsigned* Hb = (unsigned*)alloc((size_t)NNODES * 64 * 4);                // 25.6 MB packed
  short* Wb = (short*)alloc((size_t)ODIM * KDIM * 2);                      // 64 KB
  unsigned* counts = (unsigned*)alloc((size_t)NXCD * NNODES * 4);          // 3.2 MB (-> bases)
  int* chunkExcl = (int*)alloc((size_t)NNODES * 4);
  int* offsets = (int*)alloc((size_t)(NNODES + 1) * 4);
  int* blockSums = (int*)alloc((size_t)NB_SCAN * 4);
  unsigned short* rank = (unsigned short*)alloc((size_t)NEDGES * 2);  // 3.2 MB
  int2* edges = (int2*)alloc((size_t)EDGE_CAP * 8);  // 15.2 MB, padded CSR records

  hipMemsetAsync(counts, 0, (size_t)NXCD * NNODES * 4, stream);
  conv_rank_kernel<<<CONV_BLOCKS + RANK_BLOCKS, 256, 0, stream>>>(W, Wb, erow, counts, rank);
  gemm_scan1_kernel<<<NB_SCAN + GEMM_BLOCKS, 256, 0, stream>>>(X, Wb, bias, Hb,
                                                               counts, chunkExcl, blockSums);
  scan23_kernel<<<NB_SCAN, 512, 0, stream>>>(blockSums, chunkExcl, counts, offsets, edges);
  place_kernel<<<RANK_BLOCKS, 256, 0, stream>>>(erow, ecol, eval, rank, counts, edges);
  spmm_kernel<<<(NNODES + 3) / 4, 256, 0, stream>>>(offsets, edges, (const unsigned*)Hb, out);
}